// Round 2
// baseline (2362.957 us; speedup 1.0000x reference)
//
#include <hip/hip_runtime.h>
#include <cstddef>

#define EPSV 1e-5f

__device__ __forceinline__ float lrelu01(float v) { return v > 0.f ? v : 0.01f * v; }
__device__ __forceinline__ void atomAddF(float* p, float v) { unsafeAtomicAdd(p, v); }
__device__ __forceinline__ unsigned fkey(float f) {
    unsigned u = __float_as_uint(f);
    return (u & 0x80000000u) ? ~u : (u | 0x80000000u);
}

static inline unsigned cdivu(unsigned a, unsigned b) { return (a + b - 1) / b; }

// ---------------- small kernels ----------------

__global__ void k_deg(const int* __restrict__ dst, int* __restrict__ deg, int E) {
    int e = blockIdx.x * 256 + threadIdx.x;
    if (e < E) atomicAdd(&deg[dst[e]], 1);
}

__global__ void k_dinv(const int* __restrict__ deg, float* __restrict__ dinv, int n) {
    int i = blockIdx.x * 256 + threadIdx.x;
    if (i < n) dinv[i] = rsqrtf((float)(deg[i] + 1));  // +1 self loop
}

// h1 = relu(x @ c1w.T + c1b), [N,64]
__global__ void k_h1(const float* __restrict__ x, const float* __restrict__ w,
                     const float* __restrict__ b, float* __restrict__ h1, int n) {
    int t = blockIdx.x * 256 + threadIdx.x;
    int node = t >> 6, c = t & 63;
    if (node >= n) return;
    float x0 = x[node * 3], x1 = x[node * 3 + 1], x2 = x[node * 3 + 2];
    float v = x0 * w[c * 3] + x1 * w[c * 3 + 1] + x2 * w[c * 3 + 2] + b[c];
    h1[(size_t)node * 64 + c] = fmaxf(v, 0.f);
}

// per-channel sum/sumsq over nodes of z[N,128]
__global__ void k_colstats(const float* __restrict__ z, int n,
                           float* __restrict__ sum, float* __restrict__ ss) {
    int c = threadIdx.x;  // blockDim = 128
    float s = 0.f, q = 0.f;
    for (int r = blockIdx.x; r < n; r += gridDim.x) {
        float v = z[(size_t)r * 128 + c];
        s += v; q += v * v;
    }
    atomAddF(&sum[c], s); atomAddF(&ss[c], q);
}

__global__ void k_murs(const float* __restrict__ sum2, const float* __restrict__ ss2,
                       float* __restrict__ mu2, float* __restrict__ rs2, float invn) {
    int c = threadIdx.x;  // 128
    float m = sum2[c] * invn;
    float var = ss2[c] * invn - m * m;
    mu2[c] = m;
    rs2[c] = rsqrtf(var + EPSV);
}

// TNet head: g=relu((max-mu)*rs) -> fc1 relu -> fc2 relu -> fc3 + iden -> T9
__launch_bounds__(256)
__global__ void k_tnet(const float* __restrict__ sum3, const float* __restrict__ ss3,
                       const unsigned* __restrict__ maxk,
                       const float* __restrict__ f1w, const float* __restrict__ f1b,
                       const float* __restrict__ f2w, const float* __restrict__ f2b,
                       const float* __restrict__ f3w, const float* __restrict__ f3b,
                       float* __restrict__ T9, float invn) {
    __shared__ float g[1024];
    __shared__ float a1[512];
    __shared__ float a2[256];
    int tid = threadIdx.x;
    for (int c = tid; c < 1024; c += 256) {
        float m = sum3[c] * invn;
        float var = ss3[c] * invn - m * m;
        unsigned k = maxk[c];
        unsigned u = (k & 0x80000000u) ? (k & 0x7FFFFFFFu) : ~k;
        float mx = __uint_as_float(u);
        g[c] = fmaxf((mx - m) * rsqrtf(var + EPSV), 0.f);
    }
    __syncthreads();
    for (int c = tid; c < 512; c += 256) {
        const float* w = f1w + (size_t)c * 1024;
        float s = f1b[c];
        for (int k = 0; k < 1024; ++k) s = fmaf(w[k], g[k], s);
        a1[c] = fmaxf(s, 0.f);
    }
    __syncthreads();
    {
        int c = tid;
        const float* w = f2w + (size_t)c * 512;
        float s = f2b[c];
        for (int k = 0; k < 512; ++k) s = fmaf(w[k], a1[k], s);
        a2[c] = fmaxf(s, 0.f);
    }
    __syncthreads();
    if (tid < 9) {
        const float* w = f3w + (size_t)tid * 256;
        float s = f3b[tid];
        for (int k = 0; k < 256; ++k) s = fmaf(w[k], a2[k], s);
        if (tid == 0 || tid == 4 || tid == 8) s += 1.f;
        T9[tid] = s;
    }
}

// xg = lrelu((x@T) @ conv1w.T + b), written to hcat col 256.. (stride 320)
__global__ void k_xg(const float* __restrict__ x, const float* __restrict__ T9,
                     const float* __restrict__ w, const float* __restrict__ b,
                     float* __restrict__ xg, int n) {
    int t = blockIdx.x * 256 + threadIdx.x;
    int node = t >> 6, c = t & 63;
    if (node >= n) return;
    float x0 = x[node * 3], x1 = x[node * 3 + 1], x2 = x[node * 3 + 2];
    float h0 = x0 * T9[0] + x1 * T9[3] + x2 * T9[6];
    float h1 = x0 * T9[1] + x1 * T9[4] + x2 * T9[7];
    float h2 = x0 * T9[2] + x1 * T9[5] + x2 * T9[8];
    float v = h0 * w[c * 3] + h1 * w[c * 3 + 1] + h2 * w[c * 3 + 2] + b[c];
    xg[(size_t)node * 320 + c] = lrelu01(v);
}

template <int C>
__global__ void k_scatter(const int* __restrict__ src, const int* __restrict__ dst,
                          const float* __restrict__ q, float* __restrict__ agg, int E) {
    int t = blockIdx.x * 256 + threadIdx.x;
    int e = t / C;
    int c = t & (C - 1);
    if (e >= E) return;
    int s = src[e], d = dst[e];
    atomAddF(&agg[(size_t)d * C + c], q[(size_t)s * C + c]);
}

// LN over concat[nf, lrelu(dinv*(agg+q)+gcn_b)]; CH = per-half channels; wave per node
template <int CH>
__launch_bounds__(256)
__global__ void k_ln(const float* __restrict__ nf, const float* __restrict__ agg,
                     const float* __restrict__ q, const float* __restrict__ dinv,
                     const float* __restrict__ gcn_b, const float* __restrict__ lng,
                     const float* __restrict__ lnb, float* __restrict__ out, int ldo, int n) {
    int wv = threadIdx.x >> 6, lane = threadIdx.x & 63;
    int node = blockIdx.x * 4 + wv;
    if (node >= n) return;
    float di = dinv[node];
    constexpr int R = CH / 64;
    float vA[R], vB[R];
    float s = 0.f, ss = 0.f;
#pragma unroll
    for (int r = 0; r < R; ++r) {
        int c = lane + r * 64;
        float a = nf[(size_t)node * CH + c];
        float b = di * (agg[(size_t)node * CH + c] + q[(size_t)node * CH + c]) + gcn_b[c];
        b = lrelu01(b);
        vA[r] = a; vB[r] = b;
        s += a + b; ss += a * a + b * b;
    }
#pragma unroll
    for (int off = 32; off > 0; off >>= 1) {
        s += __shfl_down(s, off);
        ss += __shfl_down(ss, off);
    }
    s = __shfl(s, 0); ss = __shfl(ss, 0);
    const float inv2c = 1.f / (float)(2 * CH);
    float m = s * inv2c;
    float var = ss * inv2c - m * m;
    float rsg = rsqrtf(var + EPSV);
#pragma unroll
    for (int r = 0; r < R; ++r) {
        int c = lane + r * 64;
        out[(size_t)node * ldo + c] = (vA[r] - m) * rsg * lng[c] + lnb[c];
        out[(size_t)node * ldo + CH + c] = (vB[r] - m) * rsg * lng[CH + c] + lnb[CH + c];
    }
}

__global__ void k_const4(const float* __restrict__ pooled, const float* __restrict__ ow,
                         const float* __restrict__ ob, float* __restrict__ c4, float invn) {
    int j = threadIdx.x >> 6, lane = threadIdx.x & 63;
    float s = 0.f;
    for (int c = lane; c < 256; c += 64) s += pooled[c] * invn * ow[j * 320 + c];
#pragma unroll
    for (int off = 32; off > 0; off >>= 1) s += __shfl_down(s, off);
    if (lane == 0) c4[j] = s + ob[j];
}

__global__ void k_out(const float* __restrict__ hcat, const float* __restrict__ ow,
                      const float* __restrict__ c4, float* __restrict__ out, int n) {
    int t = blockIdx.x * 256 + threadIdx.x;
    int node = t >> 2, j = t & 3;
    if (node >= n) return;
    const float* xg = hcat + (size_t)node * 320 + 256;
    const float* w = ow + j * 320 + 256;
    float s = c4[j];
#pragma unroll
    for (int k = 0; k < 64; ++k) s = fmaf(xg[k], w[k], s);
    out[(size_t)node * 4 + j] = s;
}

// ---------------- generic fp32 GEMM: out[n][c] = act(sum_k A[n][k]*W[c][k] + b[c]) ----------------
enum { MF_BIAS = 1, MF_RELU = 2, MF_LRELU = 4, MF_DINV = 8, MF_PREBN = 16, MF_STATS = 32, MF_COLSUM = 64, MF_STORE = 128 };

template <int MODE>
__launch_bounds__(256)
__global__ void k_gemm(const float* __restrict__ A, int lda,
                       const float* __restrict__ W,      // [C][K]
                       const float* __restrict__ bias,
                       float* __restrict__ Out, int ldo, int K,
                       const float* __restrict__ dinv,
                       const float* __restrict__ mu, const float* __restrict__ rs,
                       float* __restrict__ sum_o, float* __restrict__ ss_o,
                       unsigned* __restrict__ maxk_o, float* __restrict__ colsum_o) {
    __shared__ __align__(16) float smem[2 * 32 * 68];
    float* As = smem;             // [32][68] k-major
    float* Ws = smem + 32 * 68;   // [32][68]
    const int tid = threadIdx.x;
    const int tx = tid & 15, ty = tid >> 4;
    const int bn = blockIdx.x * 64, bc = blockIdx.y * 64;
    const int lr = tid >> 3;
    const int lk = (tid & 7) * 4;
    float acc[4][4] = {};
    for (int k0 = 0; k0 < K; k0 += 32) {
#pragma unroll
        for (int h = 0; h < 2; ++h) {
            int r = lr + h * 32;
            float4 va = *(const float4*)(A + (size_t)(bn + r) * lda + (k0 + lk));
            if (MODE & MF_PREBN) {
                va.x = fmaxf((va.x - mu[k0 + lk + 0]) * rs[k0 + lk + 0], 0.f);
                va.y = fmaxf((va.y - mu[k0 + lk + 1]) * rs[k0 + lk + 1], 0.f);
                va.z = fmaxf((va.z - mu[k0 + lk + 2]) * rs[k0 + lk + 2], 0.f);
                va.w = fmaxf((va.w - mu[k0 + lk + 3]) * rs[k0 + lk + 3], 0.f);
            }
            As[(lk + 0) * 68 + r] = va.x; As[(lk + 1) * 68 + r] = va.y;
            As[(lk + 2) * 68 + r] = va.z; As[(lk + 3) * 68 + r] = va.w;
            float4 vw = *(const float4*)(W + (size_t)(bc + r) * K + (k0 + lk));
            Ws[(lk + 0) * 68 + r] = vw.x; Ws[(lk + 1) * 68 + r] = vw.y;
            Ws[(lk + 2) * 68 + r] = vw.z; Ws[(lk + 3) * 68 + r] = vw.w;
        }
        __syncthreads();
#pragma unroll
        for (int k = 0; k < 32; ++k) {
            float4 a4 = *(const float4*)&As[k * 68 + ty * 4];
            float4 w4 = *(const float4*)&Ws[k * 68 + tx * 4];
            float av[4] = {a4.x, a4.y, a4.z, a4.w};
            float wv[4] = {w4.x, w4.y, w4.z, w4.w};
#pragma unroll
            for (int i = 0; i < 4; ++i)
#pragma unroll
                for (int j = 0; j < 4; ++j) acc[i][j] = fmaf(av[i], wv[j], acc[i][j]);
        }
        __syncthreads();
    }
    float bsv[4] = {0.f, 0.f, 0.f, 0.f};
    if (MODE & MF_BIAS) {
#pragma unroll
        for (int j = 0; j < 4; ++j) bsv[j] = bias[bc + tx * 4 + j];
    }
    float dv[4] = {1.f, 1.f, 1.f, 1.f};
    if (MODE & MF_DINV) {
#pragma unroll
        for (int i = 0; i < 4; ++i) dv[i] = dinv[bn + ty * 4 + i];
    }
    float v[4][4];
#pragma unroll
    for (int i = 0; i < 4; ++i)
#pragma unroll
        for (int j = 0; j < 4; ++j) {
            float t = acc[i][j] + bsv[j];
            if (MODE & MF_RELU) t = fmaxf(t, 0.f);
            if (MODE & MF_LRELU) t = lrelu01(t);
            if (MODE & MF_DINV) t *= dv[i];
            v[i][j] = t;
        }
    if (MODE & MF_STORE) {
#pragma unroll
        for (int i = 0; i < 4; ++i) {
            float4 o = make_float4(v[i][0], v[i][1], v[i][2], v[i][3]);
            *(float4*)(Out + (size_t)(bn + ty * 4 + i) * ldo + (bc + tx * 4)) = o;
        }
    }
    if (MODE & MF_STATS) {
        float s4[4], q4[4], m4[4];
#pragma unroll
        for (int j = 0; j < 4; ++j) {
            float s = 0.f, q = 0.f, m = -3.4e38f;
#pragma unroll
            for (int i = 0; i < 4; ++i) { float t = v[i][j]; s += t; q += t * t; m = fmaxf(m, t); }
            s4[j] = s; q4[j] = q; m4[j] = m;
        }
        float* red = smem;
#pragma unroll
        for (int j = 0; j < 4; ++j) {
            red[tid * 12 + j] = s4[j];
            red[tid * 12 + 4 + j] = q4[j];
            red[tid * 12 + 8 + j] = m4[j];
        }
        __syncthreads();
        if (ty == 0) {
#pragma unroll
            for (int j = 0; j < 4; ++j) {
                float S = 0.f, Q = 0.f, M = -3.4e38f;
                for (int t = 0; t < 16; ++t) {
                    int b2 = (t * 16 + tx) * 12;
                    S += red[b2 + j]; Q += red[b2 + 4 + j]; M = fmaxf(M, red[b2 + 8 + j]);
                }
                int c = bc + tx * 4 + j;
                atomAddF(&sum_o[c], S);
                atomAddF(&ss_o[c], Q);
                atomicMax(&maxk_o[c], fkey(M));
            }
        }
    }
    if (MODE & MF_COLSUM) {
        float* red = smem;
#pragma unroll
        for (int j = 0; j < 4; ++j) red[tid * 4 + j] = v[0][j] + v[1][j] + v[2][j] + v[3][j];
        __syncthreads();
        if (ty == 0) {
#pragma unroll
            for (int j = 0; j < 4; ++j) {
                float S = 0.f;
                for (int t = 0; t < 16; ++t) S += red[(t * 16 + tx) * 4 + j];
                atomAddF(&colsum_o[bc + tx * 4 + j], S);
            }
        }
    }
}

// ---------------- launch ----------------
// Workspace budget (the round-0 crash theory: 274 MiB overran d_ws).
// Aliased layout = (2 + 320 + 3*128) floats/node + 16 KiB = ~215.5 MiB:
//   S1 [N,128]: z2 (TNet)   -> agg1 (first N*64) -> nf2
//   S2 [N,128]: hln1        -> q2
//   S3 [N,128]: h1|q1 halves -> hmid -> agg2
//   S0 [N,320]: hcat (xg at col 256 from early on; LN2 out cols 0..255 late)

extern "C" void kernel_launch(void* const* d_in, const int* in_sizes, int n_in,
                              void* d_out, int out_size, void* d_ws, size_t ws_size,
                              hipStream_t stream) {
    const float* x   = (const float*)d_in[0];
    const int*   ei  = (const int*)d_in[1];
    const float* c1w = (const float*)d_in[2];  const float* c1b = (const float*)d_in[3];
    const float* c2w = (const float*)d_in[4];  const float* c2b = (const float*)d_in[5];
    const float* c3w = (const float*)d_in[6];  const float* c3b = (const float*)d_in[7];
    const float* f1w = (const float*)d_in[8];  const float* f1b = (const float*)d_in[9];
    const float* f2w = (const float*)d_in[10]; const float* f2b = (const float*)d_in[11];
    const float* f3w = (const float*)d_in[12]; const float* f3b = (const float*)d_in[13];
    const float* cv1w = (const float*)d_in[14]; const float* cv1b = (const float*)d_in[15];
    const float* li1w = (const float*)d_in[16]; const float* li1b = (const float*)d_in[17];
    const float* gc1w = (const float*)d_in[18]; const float* gc1b = (const float*)d_in[19];
    const float* ln1g = (const float*)d_in[20]; const float* ln1b = (const float*)d_in[21];
    const float* cv2w = (const float*)d_in[22]; const float* cv2b = (const float*)d_in[23];
    const float* li2w = (const float*)d_in[24]; const float* li2b = (const float*)d_in[25];
    const float* gc2w = (const float*)d_in[26]; const float* gc2b = (const float*)d_in[27];
    const float* ln2g = (const float*)d_in[28]; const float* ln2b = (const float*)d_in[29];
    const float* cv3w = (const float*)d_in[30]; const float* cv3b = (const float*)d_in[31];
    const float* ow  = (const float*)d_in[32]; const float* ob  = (const float*)d_in[33];
    float* out = (float*)d_out;

    const int N = in_sizes[0] / 3;
    const int E = in_sizes[1] / 2;
    const int* srcI = ei;
    const int* dstI = ei + E;

    char* base = (char*)d_ws;
    size_t off = 0;
    auto take = [&](size_t bytes) -> char* {
        char* p = base + off;
        off = (off + bytes + 255) & ~(size_t)255;
        return p;
    };
    int*   deg  = (int*)  take((size_t)N * 4);
    float* dinv = (float*)take((size_t)N * 4);
    float* sm   = (float*)take(4096 * 4);
    float* S0 = (float*)take((size_t)N * 320 * 4);
    float* S1 = (float*)take((size_t)N * 128 * 4);
    float* S2 = (float*)take((size_t)N * 128 * 4);
    float* S3 = (float*)take((size_t)N * 128 * 4);
    // aliased short-lived [N,64] views:
    float* S4 = S3;                      // h1 / nf1   (dead before conv2 writes S3)
    float* S5 = S3 + (size_t)N * 64;     // q1         (dead before conv2 writes S3)
    float* S6 = S1;                      // agg1       (z2 dead; dead before li2 writes S1)

    float* sum2 = sm;       float* ss2 = sm + 128;
    float* sum3 = sm + 256; float* ss3 = sm + 1280;
    unsigned* maxk = (unsigned*)(sm + 2304);
    float* pooled = sm + 3328;
    // zeroed region ends at 3584 floats
    float* mu2 = sm + 3584; float* rs2 = sm + 3712;
    float* T9  = sm + 3840; float* c4  = sm + 3856;

    const float invn = 1.0f / (float)N;
    const dim3 blk(256);
    const unsigned NT = (unsigned)(N / 64);  // N = 80000 -> 1250 exact

    hipMemsetAsync(deg, 0, (size_t)N * 4, stream);
    hipMemsetAsync(sm, 0, 3584 * 4, stream);

    k_deg<<<cdivu(E, 256), blk, 0, stream>>>(dstI, deg, E);
    k_dinv<<<cdivu(N, 256), blk, 0, stream>>>(deg, dinv, N);

    // ---- TNet ----
    k_h1<<<cdivu((unsigned)N * 64, 256), blk, 0, stream>>>(x, c1w, c1b, S4, N);
    k_gemm<(MF_BIAS | MF_STORE)><<<dim3(NT, 2), blk, 0, stream>>>(
        S4, 64, c2w, c2b, S1, 128, 64, nullptr, nullptr, nullptr, nullptr, nullptr, nullptr, nullptr);
    k_colstats<<<256, 128, 0, stream>>>(S1, N, sum2, ss2);
    k_murs<<<1, 128, 0, stream>>>(sum2, ss2, mu2, rs2, invn);
    k_gemm<(MF_BIAS | MF_PREBN | MF_STATS)><<<dim3(NT, 16), blk, 0, stream>>>(
        S1, 128, c3w, c3b, nullptr, 0, 128, nullptr, mu2, rs2, sum3, ss3, maxk, nullptr);
    k_tnet<<<1, 256, 0, stream>>>(sum3, ss3, maxk, f1w, f1b, f2w, f2b, f3w, f3b, T9, invn);
    k_xg<<<cdivu((unsigned)N * 64, 256), blk, 0, stream>>>(x, T9, cv1w, cv1b, S0 + 256, N);

    // ---- GCN block 1 (C=64) ----
    k_gemm<(MF_BIAS | MF_LRELU | MF_STORE)><<<dim3(NT, 1), blk, 0, stream>>>(
        S0 + 256, 320, li1w, li1b, S4, 64, 64, nullptr, nullptr, nullptr, nullptr, nullptr, nullptr, nullptr);
    k_gemm<(MF_DINV | MF_STORE)><<<dim3(NT, 1), blk, 0, stream>>>(
        S4, 64, gc1w, nullptr, S5, 64, 64, dinv, nullptr, nullptr, nullptr, nullptr, nullptr, nullptr);
    hipMemsetAsync(S6, 0, (size_t)N * 64 * 4, stream);  // agg1 (z2 dead after c3 gemm)
    k_scatter<64><<<cdivu((unsigned)E * 64, 256), blk, 0, stream>>>(srcI, dstI, S5, S6, E);
    k_ln<64><<<cdivu(N, 4), blk, 0, stream>>>(S4, S6, S5, dinv, gc1b, ln1g, ln1b, S2, 128, N);
    k_gemm<(MF_BIAS | MF_LRELU | MF_STORE)><<<dim3(NT, 2), blk, 0, stream>>>(
        S2, 128, cv2w, cv2b, S3, 128, 128, nullptr, nullptr, nullptr, nullptr, nullptr, nullptr, nullptr);

    // ---- GCN block 2 (C=128) ----
    k_gemm<(MF_BIAS | MF_LRELU | MF_STORE)><<<dim3(NT, 2), blk, 0, stream>>>(
        S3, 128, li2w, li2b, S1, 128, 128, nullptr, nullptr, nullptr, nullptr, nullptr, nullptr, nullptr);
    k_gemm<(MF_DINV | MF_STORE)><<<dim3(NT, 2), blk, 0, stream>>>(
        S1, 128, gc2w, nullptr, S2, 128, 128, dinv, nullptr, nullptr, nullptr, nullptr, nullptr, nullptr);
    hipMemsetAsync(S3, 0, (size_t)N * 128 * 4, stream);  // agg2 (hmid dead after li2)
    k_scatter<128><<<cdivu((unsigned)E * 128, 256), blk, 0, stream>>>(srcI, dstI, S2, S3, E);
    k_ln<128><<<cdivu(N, 4), blk, 0, stream>>>(S1, S3, S2, dinv, gc2b, ln2g, ln2b, S0, 320, N);

    // ---- conv3 (K=320 -> 256) with fused column-sum (pooled), no store ----
    k_gemm<(MF_BIAS | MF_LRELU | MF_COLSUM)><<<dim3(NT, 4), blk, 0, stream>>>(
        S0, 320, cv3w, cv3b, nullptr, 0, 320, nullptr, nullptr, nullptr, nullptr, nullptr, nullptr, pooled);

    // ---- head ----
    k_const4<<<1, 256, 0, stream>>>(pooled, ow, ob, c4, invn);
    k_out<<<cdivu((unsigned)N * 4, 256), blk, 0, stream>>>(S0, ow, c4, out, N);
}